// Round 11
// baseline (239.257 us; speedup 1.0000x reference)
//
#include <hip/hip_runtime.h>
#include <hip/hip_bf16.h>

// MultiheadAttention: x[4,2048,1024] fp32 -> out fp32. Internal bf16 MFMA.
// R23: attn_k reverted to R21 verbatim (R22's KVBLK=128 brought conflicts
// back 0->4.19e6 and cost 5 us; 256B V rows halved per-phase bank span).
// prep_k kept (R22's merge gained ~7.5 us). qkv_gemm_k: BK=64 2-barrier ->
// BK=32 double-buffered single-barrier (attn's proven pattern): stage k+1
// issued under compute of k; LDS 2x(16KB A + 8KB B) = 48 KB, 3 blocks/CU
// retained. Chunk swizzle c ^= (row>>1)&3 (64B rows); at read sites reduces
// to lane-constant (lc>>1)&3 -> 2-way aliasing only (free, m136).

#define DIM  1024
#define SEQ  2048
#define BATCH 4
#define NH   16
#define HD   64

typedef __bf16 bf16x8 __attribute__((ext_vector_type(8)));
typedef __bf16 bf16x2 __attribute__((ext_vector_type(2)));
typedef short  s16x4  __attribute__((ext_vector_type(4)));
typedef float  f32x4  __attribute__((ext_vector_type(4)));
typedef float  f32x16 __attribute__((ext_vector_type(16)));
typedef unsigned int uint4v __attribute__((ext_vector_type(4)));

static __device__ __forceinline__ f32x16 mfma32(bf16x8 a, bf16x8 b, f32x16 c) {
    return __builtin_amdgcn_mfma_f32_32x32x16_bf16(a, b, c, 0, 0, 0);
}

static __device__ __forceinline__ unsigned short f2b(float f) {
    __bf16 h = (__bf16)f;                      // RNE convert
    return __builtin_bit_cast(unsigned short, h);
}

static __device__ __forceinline__ void load_lds16(const unsigned short* g,
                                                  unsigned short* l) {
    __builtin_amdgcn_global_load_lds(
        (const __attribute__((address_space(1))) void*)g,
        (__attribute__((address_space(3))) void*)l, 16, 0, 0);
}

// ---------------------------------------------------------------------------
// Kernel P: merged prep. blocks 0..4095: x fp32 -> bf16 (8 elems/thread).
// blocks 4096..7167: Wt[n][k] = bf16(W[k][n]) tile transpose (32x32, 3 z).
// ---------------------------------------------------------------------------
__global__ __launch_bounds__(256) void prep_k(
    const float* __restrict__ x, unsigned short* __restrict__ xb,
    const float* __restrict__ Wq, const float* __restrict__ Wk,
    const float* __restrict__ Wv, unsigned short* __restrict__ Wt) {
    __shared__ unsigned short t[32][33];
    int bid = blockIdx.x, tid = threadIdx.x;
    if (bid < 4096) {
        size_t i = ((size_t)bid * 256 + tid) * 8;
        const f32x4* s = (const f32x4*)(x + i);
        f32x4 a0 = s[0], a1 = s[1];
        bf16x8 v;
        for (int j = 0; j < 4; j++) { v[j] = (__bf16)a0[j]; v[4 + j] = (__bf16)a1[j]; }
        *(bf16x8*)(xb + i) = v;
    } else {
        int r = bid - 4096;                    // 0..3071
        int z = r >> 10;                       // 1024 tiles per z
        int by = (r >> 5) & 31, bx = r & 31;
        const float* W = (z == 0) ? Wq : (z == 1) ? Wk : Wv;
        unsigned short* o = Wt + (size_t)z * DIM * DIM;
        int tx = tid & 31, ty = tid >> 5;
        int n0 = bx * 32, k0 = by * 32;
        for (int j = ty; j < 32; j += 8)
            t[j][tx] = f2b(W[(size_t)(k0 + j) * DIM + n0 + tx]);
        __syncthreads();
        for (int j = ty; j < 32; j += 8)
            o[(size_t)(n0 + j) * DIM + k0 + tx] = t[tx][j];
    }
}

// ---------------------------------------------------------------------------
// Kernel 1: fused QKV projection (R23: BK=32, double-buffered, 1 barrier/step).
// 1D grid 768, 512 thr. 256x128 tile. XCD-panel clustering (bid&7 = XCD).
// Staging: global_load_lds, linear dest, source chunk ^= (row>>1)&3.
// z=0 -> Q scaled log2e/8, z=1 -> K, z=2 -> V^T via per-wave LDS transpose.
// ---------------------------------------------------------------------------
__global__ __launch_bounds__(512) void qkv_gemm_k(
    const unsigned short* __restrict__ xb,
    const unsigned short* __restrict__ WtBase,
    const float* __restrict__ bq,
    const float* __restrict__ bk,
    const float* __restrict__ bv,
    unsigned short* __restrict__ Qo,
    unsigned short* __restrict__ Ko,
    unsigned short* __restrict__ Vto) {
    // 2 buffers x (A 256x32 + B 128x32) shorts = 2 x 24 KB = 48 KB
    __shared__ __align__(16) unsigned short AB[2 * 12288];
    int tid = threadIdx.x, wave = tid >> 6, lane = tid & 63;
    int quad = lane >> 4, lc = lane & 15;
    // XCD-panel decode
    int bid = blockIdx.x;
    int xcd = bid & 7, slot = bid >> 3;
    int pp = slot / 24, i = slot - pp * 24;
    int p = pp * 8 + xcd;
    int z = i >> 3, nx = i & 7;
    int m0 = p * 256, n0 = nx * 128;
    const unsigned short* Wt = WtBase + (size_t)z * DIM * DIM;
    int wm = (wave >> 1) * 64, wn = (wave & 1) * 64;
    int off = ((quad ^ ((lc >> 1) & 3))) * 8;   // read chunk (2-way free alias)

    // staging coords: slot s -> row s>>2, chunk s&3; src chunk ^= (row>>1)&3
    int ar0 = tid >> 2, ac0 = (tid & 3) ^ ((ar0 >> 1) & 3);
    int ar1 = (tid + 512) >> 2, ac1 = (tid & 3) ^ ((ar1 >> 1) & 3);
    // B rows: 128 rows x 4 chunks = 512 slots
    int br0 = tid >> 2, bc0 = (tid & 3) ^ ((br0 >> 1) & 3);

    f32x4 acc[4][4] = {};

    // prologue: stage k0=0 into buffer 0
    {
        unsigned short* As = AB;
        unsigned short* Bs = AB + 8192;
        load_lds16(xb + (size_t)(m0 + ar0) * DIM + ac0 * 8, &As[tid * 8]);
        load_lds16(xb + (size_t)(m0 + ar1) * DIM + ac1 * 8, &As[(tid + 512) * 8]);
        load_lds16(Wt + (size_t)(n0 + br0) * DIM + bc0 * 8, &Bs[tid * 8]);
    }

    for (int k0 = 0; k0 < DIM; k0 += 32) {
        int cur = (k0 >> 5) & 1;
        unsigned short* As = AB + cur * 12288;
        unsigned short* Bs = As + 8192;
        __syncthreads();   // cur staged (vmcnt drained) + other buffer free

        if (k0 + 32 < DIM) {   // stage next K-step under compute
            unsigned short* An = AB + (cur ^ 1) * 12288;
            unsigned short* Bn = An + 8192;
            load_lds16(xb + (size_t)(m0 + ar0) * DIM + k0 + 32 + ac0 * 8,
                       &An[tid * 8]);
            load_lds16(xb + (size_t)(m0 + ar1) * DIM + k0 + 32 + ac1 * 8,
                       &An[(tid + 512) * 8]);
            load_lds16(Wt + (size_t)(n0 + br0) * DIM + k0 + 32 + bc0 * 8,
                       &Bn[tid * 8]);
        }

        bf16x8 af[4], bfr[4];
        #pragma unroll
        for (int mt = 0; mt < 4; mt++)
            af[mt] = *(const bf16x8*)&As[(wm + mt * 16 + lc) * 32 + off];
        #pragma unroll
        for (int nt = 0; nt < 4; nt++)
            bfr[nt] = *(const bf16x8*)&Bs[(wn + nt * 16 + lc) * 32 + off];
        #pragma unroll
        for (int mt = 0; mt < 4; mt++)
            #pragma unroll
            for (int nt = 0; nt < 4; nt++)
                acc[mt][nt] = __builtin_amdgcn_mfma_f32_16x16x32_bf16(
                    af[mt], bfr[nt], acc[mt][nt], 0, 0, 0);
    }

    const float* bias = (z == 0) ? bq : (z == 1) ? bk : bv;
    float scale = (z == 0) ? 0.18033688011112042f : 1.0f;  // (1/8)*log2(e)

    if (z != 2) {
        for (int nt = 0; nt < 4; nt++) {
            int n = n0 + wn + nt * 16 + lc;
            float bvl = bias[n];
            int h = n >> 6, d = n & 63;
            for (int mt = 0; mt < 4; mt++) {
                for (int r = 0; r < 4; r++) {
                    int m = m0 + wm + mt * 16 + quad * 4 + r;
                    int b = m >> 11, s = m & 2047;
                    unsigned short ub = f2b((acc[mt][nt][r] + bvl) * scale);
                    if (z == 0)
                        Qo[((size_t)(b * NH + h) * SEQ + s) * HD + d] = ub;
                    else
                        Ko[((size_t)(b * NH + h) * SEQ + s) * HD + d] = ub;
                }
            }
        }
    } else {
        // V^T: per-wave LDS transpose (16 m x 64 n slices), coalesced stores.
        __syncthreads();
        unsigned short* T = AB + wave * 1024;
        int h = (n0 + wn) >> 6;
        int d = lane;
        for (int mt = 0; mt < 4; mt++) {
            for (int nt = 0; nt < 4; nt++) {
                int n = n0 + wn + nt * 16 + lc;
                float bvl = bias[n];
                s16x4 v4;
                for (int r = 0; r < 4; r++)
                    v4[r] = (short)f2b(acc[mt][nt][r] + bvl);
                *(s16x4*)&T[(nt * 16 + lc) * 16 + quad * 4] = v4;
            }
            int s_base = m0 + wm + mt * 16;
            int b = s_base >> 11, sl = s_base & 2047;
            unsigned short* dst =
                Vto + ((size_t)(b * NH + h) * HD + d) * SEQ + sl;
            uint4v t0 = *(const uint4v*)&T[d * 16];
            uint4v t1 = *(const uint4v*)&T[d * 16 + 8];
            *(uint4v*)&dst[0] = t0;
            *(uint4v*)&dst[8] = t1;
        }
    }
}

// ---------------------------------------------------------------------------
// Kernel 2: flash attention (R21 verbatim, 32x32x16 MFMA). 512 blocks, 512 thr.
// Block = 256 q; wave owns 32 q (q = wave*32 + lane&31). XCD-banded grid.
// K/V double-buffered LDS 64x64 each; swizzle s(row)=(row^(row>>3))&7.
// QK: D[key][q] = K x Q (8 mfma32). P->B-frag via 4 permlane32_swap/key-block.
// PV: o^T[d][q] = V^T x P (8 mfma32). Denominator: A=ones (4 mfma32).
// ---------------------------------------------------------------------------
__global__ __launch_bounds__(512) void attn_k(
    const unsigned short* __restrict__ Q,
    const unsigned short* __restrict__ K,
    const unsigned short* __restrict__ Vt,
    float* __restrict__ out) {
    // 2 buffers x (K 64x64 + V^T 64x64) shorts = 2 x 16 KB
    __shared__ __align__(16) unsigned short KV[2 * 8192];

    int tid = threadIdx.x, wave = tid >> 6, lane = tid & 63;
    int l31 = lane & 31, hi = lane >> 5;
    // XCD-banded decode: bijective bid -> (bh, qt); 512 blocks, 8 qt per bh
    int bid = blockIdx.x;
    int j = bid >> 3;
    int bh = (bid & 7) * 8 + (j >> 3);
    int qt = j & 7;
    int b = bh >> 4, h = bh & 15;
    const unsigned short* Qg = Q + ((size_t)bh * SEQ + qt * 256) * HD;
    const unsigned short* Kg = K + (size_t)bh * SEQ * HD;
    const unsigned short* Vg = Vt + (size_t)bh * HD * SEQ;

    // staging coords: 512 threads cover one 64x8-chunk tile exactly.
    int sr = tid >> 3, scc = tid & 7;
    int kcc = scc ^ ((sr ^ (sr >> 3)) & 7);

    // Q fragments (B-frag): B[k=d][n=q]: q = wave*32+l31, d = ds*16 + hi*8 + j
    bf16x8 qf[4];
    {
        const unsigned short* q0 = Qg + (size_t)(wave * 32 + l31) * HD + hi * 8;
        #pragma unroll
        for (int ds_ = 0; ds_ < 4; ds_++)
            qf[ds_] = *(const bf16x8*)(q0 + ds_ * 16);
    }

    f32x16 o[2] = {};     // [db]: O^T[d=db*32+row32][q=l31]
    f32x16 racc = {};     // denominator (all 16 rows identical)
    bf16x8 ones8;
    #pragma unroll
    for (int t = 0; t < 8; t++) ones8[t] = (__bf16)1.0f;

    // row-swizzle terms for this lane's MFMA A-frag reads (row = base + l31)
    int swzK0 = ((l31 ^ (l31 >> 3)) & 7);           // rows 0..31
    int r32 = 32 + l31;
    int swzK1 = ((r32 ^ (r32 >> 3)) & 7);           // rows 32..63

    // prologue: stage tile 0 into buffer 0 (linear dest, swizzled source)
    {
        unsigned short* Ks = KV;
        unsigned short* Vs = KV + 4096;
        load_lds16(Kg + (size_t)sr * HD + kcc * 8, &Ks[tid * 8]);
        load_lds16(Vg + (size_t)sr * SEQ + kcc * 8, &Vs[tid * 8]);
    }

    for (int t0 = 0; t0 < SEQ; t0 += 64) {
        int cur = (t0 >> 6) & 1;
        unsigned short* Ks = KV + cur * 8192;
        unsigned short* Vs = Ks + 4096;
        __syncthreads();   // drains prior gload_lds (compiler vmcnt) + hazard

        if (t0 + 64 < SEQ) {   // stage next tile into other buffer
            unsigned short* Kn = KV + (cur ^ 1) * 8192;
            unsigned short* Vn = Kn + 4096;
            load_lds16(Kg + (size_t)(t0 + 64 + sr) * HD + kcc * 8, &Kn[tid * 8]);
            load_lds16(Vg + (size_t)sr * SEQ + (t0 + 64) + kcc * 8, &Vn[tid * 8]);
        }

        __builtin_amdgcn_s_setprio(1);
        #pragma unroll
        for (int kb = 0; kb < 2; kb++) {
            // ---- QK^T: D[key = kb*32 + row32][q = l31], K over d (4 x 16)
            int krow = kb * 32 + l31;
            int ksw = (kb == 0) ? swzK0 : swzK1;
            f32x16 sc = {};
            #pragma unroll
            for (int ds_ = 0; ds_ < 4; ds_++) {
                bf16x8 kfrag = *(const bf16x8*)
                    &Ks[krow * 64 + ((ds_ * 2 + hi) ^ ksw) * 8];
                sc = mfma32(kfrag, qf[ds_], sc);
            }
            // ---- softmax numerator: p = exp2(sc), pack pairs via cvt_pk
            unsigned int W[8];
            #pragma unroll
            for (int rr = 0; rr < 8; rr++) {
                float p0 = __builtin_amdgcn_exp2f(sc[2 * rr]);
                float p1 = __builtin_amdgcn_exp2f(sc[2 * rr + 1]);
                bf16x2 pk; pk[0] = (__bf16)p0; pk[1] = (__bf16)p1;
                W[rr] = __builtin_bit_cast(unsigned int, pk);
            }
            // ---- P redistribution: half-swap with lane+-32 partner.
            asm volatile("v_permlane32_swap_b32 %0, %1"
                         : "+v"(W[0]), "+v"(W[2]));
            asm volatile("v_permlane32_swap_b32 %0, %1"
                         : "+v"(W[1]), "+v"(W[3]));
            asm volatile("v_permlane32_swap_b32 %0, %1"
                         : "+v"(W[4]), "+v"(W[6]));
            asm volatile("v_permlane32_swap_b32 %0, %1"
                         : "+v"(W[5]), "+v"(W[7]));
            bf16x8 fA = __builtin_bit_cast(bf16x8,
                            (uint4v){W[0], W[1], W[2], W[3]});
            bf16x8 fB = __builtin_bit_cast(bf16x8,
                            (uint4v){W[4], W[5], W[6], W[7]});
            // ---- denominator on MFMA pipe (A = ones)
            racc = mfma32(ones8, fA, racc);
            racc = mfma32(ones8, fB, racc);
            // ---- PV: o[db] += V^T-frag x P-frag  (K=16 per mfma)
            #pragma unroll
            for (int db = 0; db < 2; db++) {
                int vrow = db * 32 + l31;
                int vsw = (db == 0) ? swzK0 : swzK1;
                bf16x8 v0 = *(const bf16x8*)
                    &Vs[vrow * 64 + ((kb * 4 + hi) ^ vsw) * 8];
                bf16x8 v1 = *(const bf16x8*)
                    &Vs[vrow * 64 + ((kb * 4 + 2 + hi) ^ vsw) * 8];
                o[db] = mfma32(v0, fA, o[db]);
                o[db] = mfma32(v1, fB, o[db]);
            }
        }
        __builtin_amdgcn_s_setprio(0);
    }

    // denominator: all 16 racc rows identical; racc[0] = full sum for q=l31
    float inv = 1.0f / racc[0];

    // stores: row q = qt*256 + wave*32 + l31; d = db*32 + 8*rr + 4*hi + {0..3}
    float* orow = out + ((size_t)b * SEQ + qt * 256 + wave * 32 + l31) * DIM
                  + h * HD + hi * 4;
    #pragma unroll
    for (int db = 0; db < 2; db++) {
        #pragma unroll
        for (int rr = 0; rr < 4; rr++) {
            f32x4 s = { o[db][4 * rr], o[db][4 * rr + 1],
                        o[db][4 * rr + 2], o[db][4 * rr + 3] };
            s *= inv;
            *(f32x4*)&orow[db * 32 + rr * 8] = s;
        }
    }
}

// ---------------------------------------------------------------------------
extern "C" void kernel_launch(void* const* d_in, const int* in_sizes, int n_in,
                              void* d_out, int out_size, void* d_ws, size_t ws_size,
                              hipStream_t stream) {
    (void)in_sizes; (void)n_in; (void)out_size; (void)ws_size;
    const float* x  = (const float*)d_in[0];
    const float* Wq = (const float*)d_in[1];
    const float* bq = (const float*)d_in[2];
    const float* Wk = (const float*)d_in[3];
    const float* bk = (const float*)d_in[4];
    const float* Wv = (const float*)d_in[5];
    const float* bv = (const float*)d_in[6];

    char* ws = (char*)d_ws;
    unsigned short* Wt = (unsigned short*)ws;                             // 6 MB
    unsigned short* Qb = (unsigned short*)(ws + (size_t)6 * 1024 * 1024);
    unsigned short* Kb = Qb + (size_t)BATCH * NH * SEQ * HD;
    unsigned short* Vb = Kb + (size_t)BATCH * NH * SEQ * HD;
    unsigned short* xb = (unsigned short*)d_out;  // scratch; attn overwrites

    prep_k<<<dim3(7168), dim3(256), 0, stream>>>(x, xb, Wq, Wk, Wv, Wt);
    qkv_gemm_k<<<dim3(768), dim3(512), 0, stream>>>(xb, Wt, bq, bk, bv, Qb, Kb, Vb);
    attn_k<<<dim3(512), dim3(512), 0, stream>>>(Qb, Kb, Vb, (float*)d_out);
}